// Round 3
// baseline (2694.361 us; speedup 1.0000x reference)
//
#include <hip/hip_runtime.h>
#include <hip/hip_bf16.h>

static constexpr int TG_NN = 100000;
static constexpr int TG_NE = 1200000;
static constexpr int TG_D  = 64;
static constexpr int TG_NC = 40;
static constexpr int TG_BT = 256;

// ---- dtype-flexible load/store helpers (flag: 1 = fp32 storage, 0 = bf16) ----
__device__ __forceinline__ float tg71_ld(const void* p, long i, int isF32) {
    if (isF32) return ((const float*)p)[i];
    return __bfloat162float(((const __hip_bfloat16*)p)[i]);
}
__device__ __forceinline__ void tg71_st(void* p, long i, int isF32, float v) {
    if (isF32) ((float*)p)[i] = v;
    else ((__hip_bfloat16*)p)[i] = __float2bfloat16(v);
}

// flags[0] = edge_index stored as int64 ; flags[1] = float tensors stored as fp32
// int64 detect: hi-words of int64 node indices (<1e5) are all zero.
// fp32 detect: viewing fp32 data as bf16 puts mantissa bits into the exponent
// field at even indices -> with 2048 samples of W1 (scale 0.05), huge/NaN
// values appear w.p. ~1; genuine bf16 W1 values are all < 0.5.
__global__ void tg71_detect(const int* ei, const unsigned short* w1bits, int* flags) {
    if (threadIdx.x == 0 && blockIdx.x == 0) {
        int i64 = 1;
        for (int k = 0; k < 64; ++k) {
            if (ei[2 * k + 1] != 0) { i64 = 0; break; }
        }
        flags[0] = i64;
        int f32 = 0;
        for (int k = 0; k < 2048; ++k) {
            unsigned int bits = ((unsigned int)w1bits[k]) << 16;
            float v = __uint_as_float(bits);
            if (!(v == v) || fabsf(v) > 1e4f) { f32 = 1; break; }
        }
        flags[1] = f32;
    }
}

// Sentinel: fill d_out so a zero-output run is distinguishable from a
// partial-pipeline run. Overwritten by tg71_head when the pipeline completes.
extern "C" __global__ void TAGModel_71227737636876_kernel(void* out, const int* flags) {
    long i = (long)blockIdx.x * blockDim.x + threadIdx.x;
    if (i < (long)TG_NN * TG_NC) tg71_st(out, i, flags[1], 123.0f);
}

__global__ void tg71_edges(const int* ei, const int* flags, int* srcI, int* dstI) {
    int e = blockIdx.x * blockDim.x + threadIdx.x;
    if (e >= TG_NE) return;
    if (flags[0]) {
        srcI[e] = ei[2 * e];
        dstI[e] = ei[2 * TG_NE + 2 * e];
    } else {
        srcI[e] = ei[e];
        dstI[e] = ei[TG_NE + e];
    }
}

__global__ void tg71_zero(float* p, int n) {
    int i = blockIdx.x * blockDim.x + threadIdx.x;
    if (i < n) p[i] = 0.0f;
}

__global__ void tg71_deg(const int* dstI, float* deg) {
    int e = blockIdx.x * blockDim.x + threadIdx.x;
    if (e < TG_NE) atomicAdd(deg + dstI[e], 1.0f);
}

__global__ void tg71_dis(float* deg) {
    int i = blockIdx.x * blockDim.x + threadIdx.x;
    if (i < TG_NN) { float d = deg[i]; deg[i] = d > 0.0f ? rsqrtf(d) : 0.0f; }
}

__global__ void tg71_norm(const int* srcI, const int* dstI, const float* dis, float* nrm) {
    int e = blockIdx.x * blockDim.x + threadIdx.x;
    if (e < TG_NE) nrm[e] = dis[srcI[e]] * dis[dstI[e]];
}

// hout[dst][f] += nrm * hin[src][f]; hin = model input (dtype via flag)
__global__ void tg71_prop_in(const int* srcI, const int* dstI, const float* nrm,
                             const void* hin, const int* flags, float* hout) {
    int tid = blockIdx.x * blockDim.x + threadIdx.x;
    if (tid >= TG_NE * TG_D) return;
    int e = tid >> 6, f = tid & 63;
    float v = tg71_ld(hin, (long)srcI[e] * TG_D + f, flags[1]) * nrm[e];
    atomicAdd(hout + (long)dstI[e] * TG_D + f, v);
}

__global__ void tg71_prop_f32(const int* srcI, const int* dstI, const float* nrm,
                              const float* hin, float* hout) {
    int tid = blockIdx.x * blockDim.x + threadIdx.x;
    if (tid >= TG_NE * TG_D) return;
    int e = tid >> 6, f = tid & 63;
    float v = hin[(long)srcI[e] * TG_D + f] * nrm[e];
    atomicAdd(hout + (long)dstI[e] * TG_D + f, v);
}

// y (+)= hop @ W[koff:koff+64, :]; W row-major [256,64]; bias [64]
// mode 0: y = bias + hop@Wb ; 1: y += hop@Wb ; 2: y = relu(y + hop@Wb)
__global__ void tg71_gemm_in(const void* hop, const void* W, int koff, const void* bias,
                             const int* flags, float* y, int mode) {
    int tid = blockIdx.x * blockDim.x + threadIdx.x;
    if (tid >= TG_NN * TG_D) return;
    int fF = flags[1];
    int n = tid >> 6, j = tid & 63;
    float acc = 0.0f;
    for (int f = 0; f < TG_D; ++f)
        acc += tg71_ld(hop, (long)n * TG_D + f, fF) * tg71_ld(W, (long)(koff + f) * TG_D + j, fF);
    float base = (mode == 0) ? tg71_ld(bias, j, fF) : y[tid];
    float r = base + acc;
    if (mode == 2) r = fmaxf(r, 0.0f);
    y[tid] = r;
}

__global__ void tg71_gemm_f32(const float* hop, const void* W, int koff, const void* bias,
                              const int* flags, float* y, int mode) {
    int tid = blockIdx.x * blockDim.x + threadIdx.x;
    if (tid >= TG_NN * TG_D) return;
    int fF = flags[1];
    int n = tid >> 6, j = tid & 63;
    float acc = 0.0f;
    for (int f = 0; f < TG_D; ++f)
        acc += hop[(long)n * TG_D + f] * tg71_ld(W, (long)(koff + f) * TG_D + j, fF);
    float base = (mode == 0) ? tg71_ld(bias, j, fF) : y[tid];
    float r = base + acc;
    if (mode == 2) r = fmaxf(r, 0.0f);
    y[tid] = r;
}

// out[n][c] = bc[c] + z[n,:]·Wc[:,c]; Wc row-major [64,40]
__global__ void tg71_head(const float* z, const void* Wc, const void* bc,
                          const int* flags, void* out) {
    int tid = blockIdx.x * blockDim.x + threadIdx.x;
    if (tid >= TG_NN * TG_NC) return;
    int fF = flags[1];
    int n = tid / TG_NC;
    int c = tid - n * TG_NC;
    float acc = tg71_ld(bc, c, fF);
    for (int f = 0; f < TG_D; ++f)
        acc += z[(long)n * TG_D + f] * tg71_ld(Wc, (long)f * TG_NC + c, fF);
    tg71_st(out, tid, fF, acc);
}

extern "C" void kernel_launch(void* const* d_in, const int* in_sizes, int n_in,
                              void* d_out, int out_size, void* d_ws, size_t ws_size,
                              hipStream_t stream) {
    const void* x  = d_in[0];
    const int*  ei = (const int*)d_in[1];
    const void* W1 = d_in[2];
    const void* b1 = d_in[3];
    const void* W2 = d_in[4];
    const void* b2 = d_in[5];
    const void* Wc = d_in[6];
    const void* bc = d_in[7];

    // workspace layout (4-byte words), ~117 MB total
    int*   flags = (int*)d_ws;                    // [16]
    int*   srcI  = flags + 16;                    // [NE]
    int*   dstI  = srcI + TG_NE;                  // [NE]
    float* nrm   = (float*)(dstI + TG_NE);        // [NE]
    float* deg   = nrm + TG_NE;                   // [NN]
    float* y     = deg + TG_NN;                   // [NN*D]
    float* z     = y + (long)TG_NN * TG_D;        // [NN*D]
    float* bufA  = z + (long)TG_NN * TG_D;        // [NN*D]
    float* bufB  = bufA + (long)TG_NN * TG_D;     // [NN*D]

    const int gE  = (TG_NE + TG_BT - 1) / TG_BT;
    const int gN  = (TG_NN + TG_BT - 1) / TG_BT;
    const int gEF = (TG_NE * TG_D + TG_BT - 1) / TG_BT;
    const int gNF = (TG_NN * TG_D + TG_BT - 1) / TG_BT;
    const int gNC = (TG_NN * TG_NC + TG_BT - 1) / TG_BT;

    tg71_detect<<<1, 64, 0, stream>>>(ei, (const unsigned short*)W1, flags);
    TAGModel_71227737636876_kernel<<<gNC, TG_BT, 0, stream>>>(d_out, flags);

    tg71_edges<<<gE, TG_BT, 0, stream>>>(ei, flags, srcI, dstI);
    tg71_zero<<<gN, TG_BT, 0, stream>>>(deg, TG_NN);
    tg71_deg<<<gE, TG_BT, 0, stream>>>(dstI, deg);
    tg71_dis<<<gN, TG_BT, 0, stream>>>(deg);
    tg71_norm<<<gE, TG_BT, 0, stream>>>(srcI, dstI, deg, nrm);

    // layer 1: y = relu(concat(x, Ax, A2x, A3x) @ W1 + b1)
    tg71_gemm_in<<<gNF, TG_BT, 0, stream>>>(x, W1, 0, b1, flags, y, 0);
    tg71_zero<<<gNF, TG_BT, 0, stream>>>(bufA, TG_NN * TG_D);
    tg71_prop_in<<<gEF, TG_BT, 0, stream>>>(srcI, dstI, nrm, x, flags, bufA);
    tg71_gemm_f32<<<gNF, TG_BT, 0, stream>>>(bufA, W1, 64, b1, flags, y, 1);
    tg71_zero<<<gNF, TG_BT, 0, stream>>>(bufB, TG_NN * TG_D);
    tg71_prop_f32<<<gEF, TG_BT, 0, stream>>>(srcI, dstI, nrm, bufA, bufB);
    tg71_gemm_f32<<<gNF, TG_BT, 0, stream>>>(bufB, W1, 128, b1, flags, y, 1);
    tg71_zero<<<gNF, TG_BT, 0, stream>>>(bufA, TG_NN * TG_D);
    tg71_prop_f32<<<gEF, TG_BT, 0, stream>>>(srcI, dstI, nrm, bufB, bufA);
    tg71_gemm_f32<<<gNF, TG_BT, 0, stream>>>(bufA, W1, 192, b1, flags, y, 2);

    // layer 2: z = relu(concat(y, Ay, A2y, A3y) @ W2 + b2)
    tg71_gemm_f32<<<gNF, TG_BT, 0, stream>>>(y, W2, 0, b2, flags, z, 0);
    tg71_zero<<<gNF, TG_BT, 0, stream>>>(bufA, TG_NN * TG_D);
    tg71_prop_f32<<<gEF, TG_BT, 0, stream>>>(srcI, dstI, nrm, y, bufA);
    tg71_gemm_f32<<<gNF, TG_BT, 0, stream>>>(bufA, W2, 64, b2, flags, z, 1);
    tg71_zero<<<gNF, TG_BT, 0, stream>>>(bufB, TG_NN * TG_D);
    tg71_prop_f32<<<gEF, TG_BT, 0, stream>>>(srcI, dstI, nrm, bufA, bufB);
    tg71_gemm_f32<<<gNF, TG_BT, 0, stream>>>(bufB, W2, 128, b2, flags, z, 1);
    tg71_zero<<<gNF, TG_BT, 0, stream>>>(bufA, TG_NN * TG_D);
    tg71_prop_f32<<<gEF, TG_BT, 0, stream>>>(srcI, dstI, nrm, bufB, bufA);
    tg71_gemm_f32<<<gNF, TG_BT, 0, stream>>>(bufA, W2, 192, b2, flags, z, 2);

    // head
    tg71_head<<<gNC, TG_BT, 0, stream>>>(z, Wc, bc, flags, d_out);
}

// Round 4
// 1446.198 us; speedup vs baseline: 1.8631x; 1.8631x over previous
//
#include <hip/hip_runtime.h>
#include <hip/hip_bf16.h>

static constexpr int TG_NN = 100000;
static constexpr int TG_NE = 1200000;
static constexpr int TG_D  = 64;
static constexpr int TG_NC = 40;
static constexpr int TG_BT = 256;
static constexpr int TG_NP = (TG_NN + 1023) / 1024;  // scan blocks (98)

// ---- dtype-flexible load/store (isF32: 1 = fp32 storage, 0 = bf16) ----
__device__ __forceinline__ float tg71_ld(const void* p, long i, int isF32) {
    if (isF32) return ((const float*)p)[i];
    return __bfloat162float(((const __hip_bfloat16*)p)[i]);
}
__device__ __forceinline__ void tg71_st(void* p, long i, int isF32, float v) {
    if (isF32) ((float*)p)[i] = v;
    else ((__hip_bfloat16*)p)[i] = __float2bfloat16(v);
}

// flags[0] = edge_index is int64 ; flags[1] = float tensors are fp32
__global__ void tg71_detect(const int* ei, const unsigned short* w1bits, int* flags) {
    if (threadIdx.x == 0 && blockIdx.x == 0) {
        int i64 = 1;
        for (int k = 0; k < 64; ++k)
            if (ei[2 * k + 1] != 0) { i64 = 0; break; }
        flags[0] = i64;
        int f32 = 0;
        for (int k = 0; k < 2048; ++k) {
            float v = __uint_as_float(((unsigned int)w1bits[k]) << 16);
            if (!(v == v) || fabsf(v) > 1e4f) { f32 = 1; break; }
        }
        flags[1] = f32;
    }
}

// Sentinel fill (diagnostic; overwritten by the fused head kernel).
extern "C" __global__ void TAGModel_71227737636876_kernel(void* out, const int* flags) {
    long i = (long)blockIdx.x * blockDim.x + threadIdx.x;
    if (i < (long)TG_NN * TG_NC) tg71_st(out, i, flags[1], 123.0f);
}

__global__ void tg71_edges(const int* ei, const int* flags, int* srcI, int* dstI) {
    int e = blockIdx.x * blockDim.x + threadIdx.x;
    if (e >= TG_NE) return;
    if (flags[0]) { srcI[e] = ei[2 * e]; dstI[e] = ei[2 * TG_NE + 2 * e]; }
    else          { srcI[e] = ei[e];     dstI[e] = ei[TG_NE + e]; }
}

__global__ void tg71_zero_i(int* p, int n) {
    int i = blockIdx.x * blockDim.x + threadIdx.x;
    if (i < n) p[i] = 0;
}

__global__ void tg71_hist(const int* dstI, int* cnt) {
    int e = blockIdx.x * blockDim.x + threadIdx.x;
    if (e < TG_NE) atomicAdd(cnt + dstI[e], 1);
}

__global__ void tg71_dis(const int* cnt, float* dis) {
    int i = blockIdx.x * blockDim.x + threadIdx.x;
    if (i < TG_NN) { int c = cnt[i]; dis[i] = c > 0 ? rsqrtf((float)c) : 0.0f; }
}

// ---- hierarchical exclusive scan of cnt[NN] -> rowptr[NN+1] ----
__global__ void tg71_scan1(const int* cnt, int* rowptr, int* part) {
    __shared__ int sh[256];
    int t = threadIdx.x;
    int base = blockIdx.x * 1024 + t * 4;
    int v0 = base + 0 < TG_NN ? cnt[base + 0] : 0;
    int v1 = base + 1 < TG_NN ? cnt[base + 1] : 0;
    int v2 = base + 2 < TG_NN ? cnt[base + 2] : 0;
    int v3 = base + 3 < TG_NN ? cnt[base + 3] : 0;
    int p1 = v0, p2 = v0 + v1, p3 = v0 + v1 + v2, sum = p3 + v3;
    sh[t] = sum;
    __syncthreads();
    for (int off = 1; off < 256; off <<= 1) {
        int x = (t >= off) ? sh[t - off] : 0;
        __syncthreads();
        if (t >= off) sh[t] += x;
        __syncthreads();
    }
    int ex = sh[t] - sum;  // exclusive within block
    if (base + 0 < TG_NN) rowptr[base + 0] = ex;
    if (base + 1 < TG_NN) rowptr[base + 1] = ex + p1;
    if (base + 2 < TG_NN) rowptr[base + 2] = ex + p2;
    if (base + 3 < TG_NN) rowptr[base + 3] = ex + p3;
    if (t == 255) part[blockIdx.x] = sh[255];
}

__global__ void tg71_scan2(int* part) {
    __shared__ int sh[128];
    int t = threadIdx.x;
    int v = t < TG_NP ? part[t] : 0;
    sh[t] = v;
    __syncthreads();
    for (int off = 1; off < 128; off <<= 1) {
        int x = (t >= off) ? sh[t - off] : 0;
        __syncthreads();
        if (t >= off) sh[t] += x;
        __syncthreads();
    }
    if (t < TG_NP) part[t] = sh[t] - v;  // exclusive
}

__global__ void tg71_scan3(int* rowptr, const int* part, int* fill) {
    int i = blockIdx.x * blockDim.x + threadIdx.x;
    if (i < TG_NN) {
        int r = rowptr[i] + part[i >> 10];
        rowptr[i] = r;
        fill[i] = r;
    }
    if (i == 0) rowptr[TG_NN] = TG_NE;
}

__global__ void tg71_scatter(const int* srcI, const int* dstI, int* fill, int* srcS) {
    int e = blockIdx.x * blockDim.x + threadIdx.x;
    if (e >= TG_NE) return;
    int pos = atomicAdd(fill + dstI[e], 1);
    srcS[pos] = srcI[e];
}

// ---- propagation in scaled space: g'[n] = (1/deg[n]) * sum_{src->n} g[src] ----

// first hop: g[src] = dis[src] * h[src]; h dtype: mode 0 -> flags[1], mode 1 -> f32
__global__ void tg71_prop_first(const int* rowptr, const int* srcS, const int* cnt,
                                const float* dis, const void* h, const int* flags,
                                int mode, float* out) {
    int gid = blockIdx.x * blockDim.x + threadIdx.x;
    int n = gid >> 6, lane = gid & 63;
    int isF32 = mode ? 1 : flags[1];
    int r0 = rowptr[n], r1 = rowptr[n + 1];
    float acc = 0.0f;
    int k = r0;
    for (; k + 4 <= r1; k += 4) {
        int s0 = srcS[k], s1 = srcS[k + 1], s2 = srcS[k + 2], s3 = srcS[k + 3];
        float d0 = dis[s0], d1 = dis[s1], d2 = dis[s2], d3 = dis[s3];
        float a0 = tg71_ld(h, (long)s0 * TG_D + lane, isF32) * d0;
        float a1 = tg71_ld(h, (long)s1 * TG_D + lane, isF32) * d1;
        float a2 = tg71_ld(h, (long)s2 * TG_D + lane, isF32) * d2;
        float a3 = tg71_ld(h, (long)s3 * TG_D + lane, isF32) * d3;
        acc += (a0 + a1) + (a2 + a3);
    }
    for (; k < r1; ++k) {
        int s = srcS[k];
        acc += tg71_ld(h, (long)s * TG_D + lane, isF32) * dis[s];
    }
    int c = cnt[n];
    float inv = c > 0 ? 1.0f / (float)c : 0.0f;
    out[(long)n * TG_D + lane] = acc * inv;
}

// inner hop: plain f32 gather of g
__global__ void tg71_prop(const int* rowptr, const int* srcS, const int* cnt,
                          const float* g, float* out) {
    int gid = blockIdx.x * blockDim.x + threadIdx.x;
    int n = gid >> 6, lane = gid & 63;
    int r0 = rowptr[n], r1 = rowptr[n + 1];
    float acc = 0.0f;
    int k = r0;
    for (; k + 4 <= r1; k += 4) {
        int s0 = srcS[k], s1 = srcS[k + 1], s2 = srcS[k + 2], s3 = srcS[k + 3];
        float a0 = g[(long)s0 * TG_D + lane];
        float a1 = g[(long)s1 * TG_D + lane];
        float a2 = g[(long)s2 * TG_D + lane];
        float a3 = g[(long)s3 * TG_D + lane];
        acc += (a0 + a1) + (a2 + a3);
    }
    for (; k < r1; ++k) acc += g[(long)srcS[k] * TG_D + lane];
    int c = cnt[n];
    float inv = c > 0 ? 1.0f / (float)c : 0.0f;
    out[(long)n * TG_D + lane] = acc * inv;
}

// ---- layer 1 gemm: y = relu(b1 + h0@W1[0:64] + s*(g1@W1[64:128] + g2@W1[128:192] + g3@W1[192:256]))
// h0 = x (dtype via flags); s = sqrt(deg)
__global__ void tg71_gemm1(const void* x, const float* g1, const float* g2, const float* g3,
                           const void* W, const void* bias, const int* cnt, const int* flags,
                           float* y) {
    int tid = blockIdx.x * blockDim.x + threadIdx.x;
    int n = tid >> 6, j = tid & 63;
    int fF = flags[1];
    long nb = (long)n * TG_D;
    float a0 = 0.0f, aG = 0.0f;
#pragma unroll 8
    for (int f = 0; f < TG_D; ++f)
        a0 += tg71_ld(x, nb + f, fF) * tg71_ld(W, (long)f * TG_D + j, fF);
#pragma unroll 8
    for (int f = 0; f < TG_D; ++f)
        aG += g1[nb + f] * tg71_ld(W, (long)(64 + f) * TG_D + j, fF);
#pragma unroll 8
    for (int f = 0; f < TG_D; ++f)
        aG += g2[nb + f] * tg71_ld(W, (long)(128 + f) * TG_D + j, fF);
#pragma unroll 8
    for (int f = 0; f < TG_D; ++f)
        aG += g3[nb + f] * tg71_ld(W, (long)(192 + f) * TG_D + j, fF);
    int c = cnt[n];
    float s = c > 0 ? sqrtf((float)c) : 0.0f;
    y[tid] = fmaxf(tg71_ld(bias, j, fF) + a0 + s * aG, 0.0f);
}

// ---- layer 2 gemm + fused head: z = relu(...); out = z@Wc + bc ----
__global__ void tg71_gemm2_head(const float* y, const float* g1, const float* g2, const float* g3,
                                const void* W, const void* bias, const int* cnt,
                                const void* Wc, const void* bc, const int* flags, void* out) {
    __shared__ float sm[TG_BT];
    int tid = blockIdx.x * blockDim.x + threadIdx.x;
    int n = tid >> 6, j = tid & 63;
    int fF = flags[1];
    long nb = (long)n * TG_D;
    float a0 = 0.0f, aG = 0.0f;
#pragma unroll 8
    for (int f = 0; f < TG_D; ++f)
        a0 += y[nb + f] * tg71_ld(W, (long)f * TG_D + j, fF);
#pragma unroll 8
    for (int f = 0; f < TG_D; ++f)
        aG += g1[nb + f] * tg71_ld(W, (long)(64 + f) * TG_D + j, fF);
#pragma unroll 8
    for (int f = 0; f < TG_D; ++f)
        aG += g2[nb + f] * tg71_ld(W, (long)(128 + f) * TG_D + j, fF);
#pragma unroll 8
    for (int f = 0; f < TG_D; ++f)
        aG += g3[nb + f] * tg71_ld(W, (long)(192 + f) * TG_D + j, fF);
    int c = cnt[n];
    float s = c > 0 ? sqrtf((float)c) : 0.0f;
    float z = fmaxf(tg71_ld(bias, j, fF) + a0 + s * aG, 0.0f);
    sm[threadIdx.x] = z;
    __syncthreads();
    int wbase = threadIdx.x & ~63;  // this wave's 64 z values
    if (j < TG_NC) {
        float acc = tg71_ld(bc, j, fF);
#pragma unroll 8
        for (int f = 0; f < TG_D; ++f)
            acc += sm[wbase + f] * tg71_ld(Wc, (long)f * TG_NC + j, fF);
        tg71_st(out, (long)n * TG_NC + j, fF, acc);
    }
}

extern "C" void kernel_launch(void* const* d_in, const int* in_sizes, int n_in,
                              void* d_out, int out_size, void* d_ws, size_t ws_size,
                              hipStream_t stream) {
    const void* x  = d_in[0];
    const int*  ei = (const int*)d_in[1];
    const void* W1 = d_in[2];
    const void* b1 = d_in[3];
    const void* W2 = d_in[4];
    const void* b2 = d_in[5];
    const void* Wc = d_in[6];
    const void* bc = d_in[7];

    // workspace layout (4-byte words) ~119 MB
    int*   flags  = (int*)d_ws;                     // [16]
    int*   srcI   = flags + 16;                     // [NE]
    int*   dstI   = srcI + TG_NE;                   // [NE]
    int*   srcS   = dstI + TG_NE;                   // [NE] CSR-ordered src
    int*   cnt    = srcS + TG_NE;                   // [NN]
    float* dis    = (float*)(cnt + TG_NN);          // [NN]
    int*   rowptr = (int*)(dis + TG_NN);            // [NN+1]
    int*   fill   = rowptr + TG_NN + 1;             // [NN]
    int*   part   = fill + TG_NN;                   // [128]
    float* A      = (float*)(part + 128);           // [NN*D]
    float* B      = A + (long)TG_NN * TG_D;         // [NN*D]
    float* C      = B + (long)TG_NN * TG_D;         // [NN*D]
    float* Y      = C + (long)TG_NN * TG_D;         // [NN*D]

    const int gE  = (TG_NE + TG_BT - 1) / TG_BT;
    const int gN  = (TG_NN + TG_BT - 1) / TG_BT;
    const int gP  = TG_NN * TG_D / TG_BT;           // 25000, exact
    const int gNC = (TG_NN * TG_NC + TG_BT - 1) / TG_BT;

    tg71_detect<<<1, 64, 0, stream>>>(ei, (const unsigned short*)W1, flags);
    TAGModel_71227737636876_kernel<<<gNC, TG_BT, 0, stream>>>(d_out, flags);

    // CSR build
    tg71_edges<<<gE, TG_BT, 0, stream>>>(ei, flags, srcI, dstI);
    tg71_zero_i<<<gN, TG_BT, 0, stream>>>(cnt, TG_NN);
    tg71_hist<<<gE, TG_BT, 0, stream>>>(dstI, cnt);
    tg71_dis<<<gN, TG_BT, 0, stream>>>(cnt, dis);
    tg71_scan1<<<TG_NP, TG_BT, 0, stream>>>(cnt, rowptr, part);
    tg71_scan2<<<1, 128, 0, stream>>>(part);
    tg71_scan3<<<gN, TG_BT, 0, stream>>>(rowptr, part, fill);
    tg71_scatter<<<gE, TG_BT, 0, stream>>>(srcI, dstI, fill, srcS);

    // layer 1 (scaled-space hops from x)
    tg71_prop_first<<<gP, TG_BT, 0, stream>>>(rowptr, srcS, cnt, dis, x, flags, 0, A);
    tg71_prop<<<gP, TG_BT, 0, stream>>>(rowptr, srcS, cnt, A, B);
    tg71_prop<<<gP, TG_BT, 0, stream>>>(rowptr, srcS, cnt, B, C);
    tg71_gemm1<<<gP, TG_BT, 0, stream>>>(x, A, B, C, W1, b1, cnt, flags, Y);

    // layer 2 (scaled-space hops from y)
    tg71_prop_first<<<gP, TG_BT, 0, stream>>>(rowptr, srcS, cnt, dis, Y, flags, 1, A);
    tg71_prop<<<gP, TG_BT, 0, stream>>>(rowptr, srcS, cnt, A, B);
    tg71_prop<<<gP, TG_BT, 0, stream>>>(rowptr, srcS, cnt, B, C);
    tg71_gemm2_head<<<gP, TG_BT, 0, stream>>>(Y, A, B, C, W2, b2, cnt, Wc, bc, flags, d_out);
}